// Round 1
// baseline (838.299 us; speedup 1.0000x reference)
//
#include <hip/hip_runtime.h>

#define OUT_F 11008
#define IN_F  4096
#define M_TOT 4096   // 2*2048
#define BM    256
#define BN    256
#define BK    64
#define NKT   (IN_F / BK)    // 64 K-tiles
#define TM_N  (M_TOT / BM)   // 16
#define TN_N  (OUT_F / BN)   // 43
#define NWG   (TM_N * TN_N)  // 688 (== 86*8, XCD-divisible)

typedef __bf16 bf16;
typedef __attribute__((ext_vector_type(8))) __bf16 bf16x8;
typedef __attribute__((ext_vector_type(4))) float  floatx4;

// async global->LDS, 16B per lane; LDS dest = wave-uniform base + lane*16.
#define GLD_LDS16(g, l) __builtin_amdgcn_global_load_lds(                      \
    (const __attribute__((address_space(1))) unsigned int*)(g),                \
    (__attribute__((address_space(3))) unsigned int*)(l), 16, 0, 0)

// ---------------- pre-pass 1: dequant W to bf16 ----------------
__global__ __launch_bounds__(256) void dequant_w_kernel(
    const int* __restrict__ qw, const float* __restrict__ sc,
    bf16* __restrict__ w) {
  const int idx  = blockIdx.x * 256 + threadIdx.x;   // [0, OUT_F*IN_F/8)
  const int o    = idx >> 9;            // / (IN_F/8 = 512)
  const int iv   = idx & 511;           // vector index within row
  const float s  = sc[o * (IN_F / 128) + (iv >> 4)]; // group = (iv*8)>>7
  const int base = idx * 8;
  const int4* p  = (const int4*)(qw + base);
  const int4 q0  = p[0];
  const int4 q1  = p[1];
  bf16x8 v;
  v[0] = (bf16)((float)q0.x * s);
  v[1] = (bf16)((float)q0.y * s);
  v[2] = (bf16)((float)q0.z * s);
  v[3] = (bf16)((float)q0.w * s);
  v[4] = (bf16)((float)q1.x * s);
  v[5] = (bf16)((float)q1.y * s);
  v[6] = (bf16)((float)q1.z * s);
  v[7] = (bf16)((float)q1.w * s);
  *(bf16x8*)(w + base) = v;
}

// ---------------- pre-pass 2: cast x to bf16 ----------------
__global__ __launch_bounds__(256) void cast_x_kernel(
    const float* __restrict__ x, bf16* __restrict__ xb) {
  const int idx  = blockIdx.x * 256 + threadIdx.x;
  const int base = idx * 8;
  const float4* p = (const float4*)(x + base);
  const float4 a = p[0];
  const float4 b = p[1];
  bf16x8 v;
  v[0] = (bf16)a.x; v[1] = (bf16)a.y; v[2] = (bf16)a.z; v[3] = (bf16)a.w;
  v[4] = (bf16)b.x; v[5] = (bf16)b.y; v[6] = (bf16)b.z; v[7] = (bf16)b.w;
  *(bf16x8*)(xb + base) = v;
}

// ---------------- GEMM: 256x256 tile, BK=64, 8-phase counted-vmcnt ----------
// C[M][N] = A[M][K] * B[N][K]^T + bias.
// 512 thr = 8 waves (2M x 4N); wave owns 128x64 via acc[8][4] of 16x16x32 MFMA.
// LDS: 2 dbuf x {A,B} x 2 halves x [128][64] bf16 = 128 KiB, 1 block/CU.
// Swizzle: logical byte lb at row r lives at physical pb = lb ^ ((r&7)<<4).
//   global_load_lds writes linearly -> apply inverse on the GLOBAL source
//   chunk (c ^= r&7), apply forward XOR on ds_read addresses.
// Per K-tile (4 phases, i-pair per phase, all-j B frags resident from p0):
//   p0: 12 ds_read + stage A-h0(kt+1)->buf[nxt]   (buf[nxt] A dead since kt-1 p3)
//   p1:  4 ds_read + stage A-h1(kt+1)->buf[nxt]
//   p2:  4 ds_read + stage B-h0(kt+2)->buf[cur]   (buf[cur] B dead since kt p0)
//   p3:  4 ds_read + stage B-h1(kt+2)->buf[cur], then s_waitcnt vmcnt(4):
//        all of kt+1 landed, kt+2's two B-halves remain in flight.
// Each phase: barrier; lgkmcnt(0); setprio(1); 16 MFMA; setprio(0); barrier.
__global__ __launch_bounds__(512, 2) void gemm_bt_bias_kernel(
    const bf16* __restrict__ A, const bf16* __restrict__ B,
    const float* __restrict__ bias, float* __restrict__ C) {
  __shared__ bf16 As[2][2][128 * 64];   // 64 KiB
  __shared__ bf16 Bs[2][2][128 * 64];   // 64 KiB

  const int t    = threadIdx.x;
  const int lane = t & 63;
  const int wv   = t >> 6;
  const int wm   = wv >> 2;            // 0/1: A half (M offset /128)
  const int wn   = wv & 3;             // 0..3: N offset /64
  const int lr   = lane & 15;
  const int lq   = lane >> 4;          // 0..3

  // XCD-aware bijective swizzle (NWG % 8 == 0); tm fast so consecutive
  // blocks on one XCD share the same 2 MiB W panel (fits 4 MiB L2).
  const int bid = blockIdx.x;
  const int swz = (bid & 7) * (NWG / 8) + (bid >> 3);
  const int bm  = (swz % TM_N) * BM;
  const int bn  = (swz / TM_N) * BN;

  // ---- staging coords: thread t stages 16B slots t and t+512 of a half ----
  const int sr  = t >> 3;                 // physical row 0..63 (and +64)
  const int sc  = t & 7;                  // physical 16B chunk
  const int scx = (sc ^ (sr & 7)) * 8;    // inverse-swizzled SOURCE col (elems)
  const bf16* aStg = A + (bm + sr) * IN_F + scx;
  const bf16* bStg = B + (bn + sr) * IN_F + scx;

  auto stageA = [&](int buf, int h, int kt) {
    const bf16* g = aStg + h * 128 * IN_F + kt * BK;
    bf16* l = &As[buf][h][t * 8];
    GLD_LDS16(g, l);
    GLD_LDS16(g + 64 * IN_F, l + 4096);
  };
  auto stageB = [&](int buf, int h, int kt) {
    const bf16* g = bStg + h * 128 * IN_F + kt * BK;
    bf16* l = &Bs[buf][h][t * 8];
    GLD_LDS16(g, l);
    GLD_LDS16(g + 64 * IN_F, l + 4096);
  };

  // ---- read-side swizzled column offsets (elements within a 64-elem row) ---
  const int xsw = (lr & 7) << 4;              // row-dependent XOR (row&7==lr&7)
  const int c0b = (lq * 16) ^ xsw;            // kk=0 physical byte col
  const int e0  = c0b >> 1;
  const int e1  = (c0b ^ 64) >> 1;            // kk=1

  floatx4 acc[8][4];
#pragma unroll
  for (int i = 0; i < 8; i++)
#pragma unroll
    for (int j = 0; j < 4; j++)
      acc[i][j] = (floatx4){0.f, 0.f, 0.f, 0.f};

  // ---- prologue: kt0 fully + kt1's B halves; matches steady state ----
  stageA(0, 0, 0); stageA(0, 1, 0); stageB(0, 0, 0); stageB(0, 1, 0);
  stageB(1, 0, 1); stageB(1, 1, 1);
  asm volatile("s_waitcnt vmcnt(4)" ::: "memory");  // kt0's 8 loads landed
  __builtin_amdgcn_s_barrier();

  bf16x8 bfr[4][2];
  for (int kt = 0; kt < NKT; ++kt) {
    const int cur = kt & 1;
#pragma unroll
    for (int p = 0; p < 4; ++p) {
      // ds-read this phase's A i-pair (4 x ds_read_b128)
      bf16x8 af[2][2];
      const bf16* aBase = &As[cur][wm][0];
#pragma unroll
      for (int ii = 0; ii < 2; ++ii) {
        const int row = (2 * p + ii) * 16 + lr;
        af[ii][0] = *(const bf16x8*)&aBase[row * 64 + e0];
        af[ii][1] = *(const bf16x8*)&aBase[row * 64 + e1];
      }
      if (p == 0) {  // all B fragments for this K-tile (8 x ds_read_b128)
        const bf16* bBase = &Bs[cur][wn >> 1][(wn & 1) * (64 * 64)];
#pragma unroll
        for (int j = 0; j < 4; ++j) {
          const int row = j * 16 + lr;
          bfr[j][0] = *(const bf16x8*)&bBase[row * 64 + e0];
          bfr[j][1] = *(const bf16x8*)&bBase[row * 64 + e1];
        }
      }

      // stage exactly one half-tile (2 x global_load_lds), per schedule above
      if      (p == 0) { if (kt + 1 < NKT) stageA(cur ^ 1, 0, kt + 1); }
      else if (p == 1) { if (kt + 1 < NKT) stageA(cur ^ 1, 1, kt + 1); }
      else if (p == 2) { if (kt + 2 < NKT) stageB(cur, 0, kt + 2); }
      else             { if (kt + 2 < NKT) stageB(cur, 1, kt + 2); }

      __builtin_amdgcn_s_barrier();
      asm volatile("s_waitcnt lgkmcnt(0)" ::: "memory");
      __builtin_amdgcn_s_setprio(1);
#pragma unroll
      for (int ii = 0; ii < 2; ++ii)
#pragma unroll
        for (int j = 0; j < 4; ++j)
#pragma unroll
          for (int kk = 0; kk < 2; ++kk)
            acc[2 * p + ii][j] = __builtin_amdgcn_mfma_f32_16x16x32_bf16(
                af[ii][kk], bfr[j][kk], acc[2 * p + ii][j], 0, 0, 0);
      __builtin_amdgcn_s_setprio(0);
      if (p == 3) {
        if (kt + 2 < NKT) {
          asm volatile("s_waitcnt vmcnt(4)" ::: "memory");  // kt+1 landed
        } else {
          asm volatile("s_waitcnt vmcnt(0)" ::: "memory");  // tail drain
        }
      }
      __builtin_amdgcn_s_barrier();
    }
  }

  // ---- epilogue: C/D layout col = lane&15, row = (lane>>4)*4 + reg ----
#pragma unroll
  for (int j = 0; j < 4; ++j) {
    const int col = bn + wn * 64 + j * 16 + lr;
    const float bv = bias[col];
#pragma unroll
    for (int i = 0; i < 8; ++i) {
      const int row0 = bm + wm * 128 + i * 16 + lq * 4;
#pragma unroll
      for (int r = 0; r < 4; ++r)
        __builtin_nontemporal_store(
            acc[i][j][r] + bv, &C[(size_t)(row0 + r) * OUT_F + col]);
    }
  }
}

extern "C" void kernel_launch(void* const* d_in, const int* in_sizes, int n_in,
                              void* d_out, int out_size, void* d_ws, size_t ws_size,
                              hipStream_t stream) {
  const float* x    = (const float*)d_in[0];  // [2,2048,4096] fp32
  const int*   qw   = (const int*)d_in[1];    // [11008,4096] int32 in [-8,7]
  const float* sc   = (const float*)d_in[2];  // [11008,32] fp32
  const float* bias = (const float*)d_in[3];  // [11008] fp32
  float* out = (float*)d_out;                 // [2,2048,11008] fp32

  bf16* wq = (bf16*)d_ws;
  bf16* xb = (bf16*)((char*)d_ws + (size_t)OUT_F * IN_F * sizeof(bf16));

  dequant_w_kernel<<<(OUT_F * IN_F / 8) / 256, 256, 0, stream>>>(qw, sc, wq);
  cast_x_kernel<<<(M_TOT * IN_F / 8) / 256, 256, 0, stream>>>(x, xb);

  gemm_bt_bias_kernel<<<dim3(NWG), 512, 0, stream>>>(xb, wq, bias, out);
}

// Round 2
// 769.124 us; speedup vs baseline: 1.0899x; 1.0899x over previous
//
#include <hip/hip_runtime.h>

#define OUT_F 11008
#define IN_F  4096
#define M_TOT 4096   // 2*2048
#define BM    256
#define BN    256
#define BK    64
#define NKT   (IN_F / BK)    // 64 K-tiles
#define TM_N  (M_TOT / BM)   // 16
#define TN_N  (OUT_F / BN)   // 43
#define NWG   (TM_N * TN_N)  // 688 (== 86*8, XCD-divisible)

typedef __bf16 bf16;
typedef __attribute__((ext_vector_type(8))) __bf16 bf16x8;
typedef __attribute__((ext_vector_type(4))) float  floatx4;

// async global->LDS, 16B per lane; LDS dest = wave-uniform base + lane*16.
#define GLD_LDS16(g, l) __builtin_amdgcn_global_load_lds(                      \
    (const __attribute__((address_space(1))) unsigned int*)(g),                \
    (__attribute__((address_space(3))) unsigned int*)(l), 16, 0, 0)

// ---------------- pre-pass 1: dequant W to bf16 ----------------
__global__ __launch_bounds__(256) void dequant_w_kernel(
    const int* __restrict__ qw, const float* __restrict__ sc,
    bf16* __restrict__ w) {
  const int idx  = blockIdx.x * 256 + threadIdx.x;   // [0, OUT_F*IN_F/8)
  const int o    = idx >> 9;            // / (IN_F/8 = 512)
  const int iv   = idx & 511;           // vector index within row
  const float s  = sc[o * (IN_F / 128) + (iv >> 4)]; // group = (iv*8)>>7
  const int base = idx * 8;
  const int4* p  = (const int4*)(qw + base);
  const int4 q0  = p[0];
  const int4 q1  = p[1];
  bf16x8 v;
  v[0] = (bf16)((float)q0.x * s);
  v[1] = (bf16)((float)q0.y * s);
  v[2] = (bf16)((float)q0.z * s);
  v[3] = (bf16)((float)q0.w * s);
  v[4] = (bf16)((float)q1.x * s);
  v[5] = (bf16)((float)q1.y * s);
  v[6] = (bf16)((float)q1.z * s);
  v[7] = (bf16)((float)q1.w * s);
  *(bf16x8*)(w + base) = v;
}

// ---------------- pre-pass 2: cast x to bf16 ----------------
__global__ __launch_bounds__(256) void cast_x_kernel(
    const float* __restrict__ x, bf16* __restrict__ xb) {
  const int idx  = blockIdx.x * 256 + threadIdx.x;
  const int base = idx * 8;
  const float4* p = (const float4*)(x + base);
  const float4 a = p[0];
  const float4 b = p[1];
  bf16x8 v;
  v[0] = (bf16)a.x; v[1] = (bf16)a.y; v[2] = (bf16)a.z; v[3] = (bf16)a.w;
  v[4] = (bf16)b.x; v[5] = (bf16)b.y; v[6] = (bf16)b.z; v[7] = (bf16)b.w;
  *(bf16x8*)(xb + base) = v;
}

// ---------------- GEMM: 256x256, BK=64, 8-phase, frag-prefetch ----------
// C[M][N] = A[M][K] * B[N][K]^T + bias.  512 thr = 8 waves (2M x 4N); wave
// owns 128x64 via acc[8][4] of 16x16x32 MFMA.
// Key change vs r1 (28% MfmaUtil): every phase's A fragments are ds_read
// ONE PHASE EARLY (afA/afB ping-pong), so the LDS drain of phase p+1
// overlaps the MFMA cluster of phase p.  No explicit lgkmcnt asm — the
// compiler emits fine-grained per-operand lgkmcnt(N) waits.
// Staging schedule per tile kt (2 GLD_LDS each):
//   p0: A-h0(kt+1)->nxt   p1: A-h1(kt+1)->nxt
//   p2: B-h0(kt+2)->cur   p3: B-h1(kt+2)->cur, then vmcnt(4):
//       A(kt+1)+B(kt+1) landed; B(kt+2)'s 4 loads stay in flight.
// Cross-wave safety: next-tile fragment reads are issued only AFTER the
// p3 barrier (every wave has executed its vmcnt(4) before that barrier).
__global__ __launch_bounds__(512, 2) void gemm_bt_bias_kernel(
    const bf16* __restrict__ A, const bf16* __restrict__ B,
    const float* __restrict__ bias, float* __restrict__ C) {
  __shared__ bf16 As[2][2][128 * 64];   // 64 KiB
  __shared__ bf16 Bs[2][2][128 * 64];   // 64 KiB

  const int t    = threadIdx.x;
  const int lane = t & 63;
  const int wv   = t >> 6;
  const int wm   = wv >> 2;            // 0/1: A half (M offset /128)
  const int wn   = wv & 3;             // 0..3: N offset /64
  const int lr   = lane & 15;
  const int lq   = lane >> 4;          // 0..3

  // XCD-aware bijective swizzle (NWG % 8 == 0); tm fast so consecutive
  // blocks on one XCD share the same 2 MiB W panel.
  const int bid = blockIdx.x;
  const int swz = (bid & 7) * (NWG / 8) + (bid >> 3);
  const int bm  = (swz % TM_N) * BM;
  const int bn  = (swz / TM_N) * BN;

  // ---- staging coords: thread t stages 16B slots t and t+512 of a half ----
  const int sr  = t >> 3;                 // physical row 0..63 (and +64)
  const int sc  = t & 7;                  // physical 16B chunk
  const int scx = (sc ^ (sr & 7)) * 8;    // inverse-swizzled SOURCE col (elems)
  const bf16* aStg = A + (bm + sr) * IN_F + scx;
  const bf16* bStg = B + (bn + sr) * IN_F + scx;

#define STAGE_A(BUF, H, KT)                                                  \
  { const bf16* g_ = aStg + (H) * 128 * IN_F + (KT) * BK;                    \
    GLD_LDS16(g_, &As[BUF][H][t * 8]);                                       \
    GLD_LDS16(g_ + 64 * IN_F, &As[BUF][H][t * 8 + 4096]); }
#define STAGE_B(BUF, H, KT)                                                  \
  { const bf16* g_ = bStg + (H) * 128 * IN_F + (KT) * BK;                    \
    GLD_LDS16(g_, &Bs[BUF][H][t * 8]);                                       \
    GLD_LDS16(g_ + 64 * IN_F, &Bs[BUF][H][t * 8 + 4096]); }

  // ---- read-side swizzled column offsets (elements within a 64-elem row) ---
  const int xsw = (lr & 7) << 4;              // row-dependent XOR
  const int c0b = (lq * 16) ^ xsw;            // kk=0 physical byte col
  const int e0  = c0b >> 1;
  const int e1  = (c0b ^ 64) >> 1;            // kk=1

  floatx4 acc[8][4];
#pragma unroll
  for (int i = 0; i < 8; i++)
#pragma unroll
    for (int j = 0; j < 4; j++)
      acc[i][j] = (floatx4){0.f, 0.f, 0.f, 0.f};

  bf16x8 afA[2][2], afB[2][2], bfr[4][2];

#define READ_AF(DST, CURB, I0)                                               \
  { const bf16* aB_ = &As[CURB][wm][0];                                      \
    _Pragma("unroll") for (int ii_ = 0; ii_ < 2; ++ii_) {                    \
      const int row_ = ((I0) + ii_) * 16 + lr;                               \
      DST[ii_][0] = *(const bf16x8*)&aB_[row_ * 64 + e0];                    \
      DST[ii_][1] = *(const bf16x8*)&aB_[row_ * 64 + e1]; } }

#define READ_BF(CURB)                                                        \
  { const bf16* bB_ = &Bs[CURB][wn >> 1][(wn & 1) * (64 * 64)];              \
    _Pragma("unroll") for (int j_ = 0; j_ < 4; ++j_) {                       \
      const int row_ = j_ * 16 + lr;                                         \
      bfr[j_][0] = *(const bf16x8*)&bB_[row_ * 64 + e0];                     \
      bfr[j_][1] = *(const bf16x8*)&bB_[row_ * 64 + e1]; } }

#define MFMA_PH(AFS, I0)                                                     \
  __builtin_amdgcn_s_setprio(1);                                             \
  _Pragma("unroll") for (int ii_ = 0; ii_ < 2; ++ii_)                        \
    _Pragma("unroll") for (int j_ = 0; j_ < 4; ++j_)                         \
      _Pragma("unroll") for (int kk_ = 0; kk_ < 2; ++kk_)                    \
        acc[(I0) + ii_][j_] = __builtin_amdgcn_mfma_f32_16x16x32_bf16(       \
            AFS[ii_][kk_], bfr[j_][kk_], acc[(I0) + ii_][j_], 0, 0, 0);      \
  __builtin_amdgcn_s_setprio(0);

  // ---- prologue: kt0 fully + kt1's B halves; then first fragments ----
  STAGE_A(0, 0, 0) STAGE_A(0, 1, 0) STAGE_B(0, 0, 0) STAGE_B(0, 1, 0)
  STAGE_B(1, 0, 1) STAGE_B(1, 1, 1)
  asm volatile("s_waitcnt vmcnt(4)" ::: "memory");  // kt0's 8 loads landed
  __builtin_amdgcn_s_barrier();
  READ_AF(afA, 0, 0)
  READ_BF(0)

  for (int ktb = 0; ktb < NKT; ktb += 2) {
#define TILE_BODY(CUR, NXT, KT)                                              \
    { const int kt_ = (KT);                                                  \
      /* ---- p0: MFMA i0-1 (afA);  read afB(i2-3); stage A-h0(kt+1) ---- */ \
      READ_AF(afB, CUR, 2)                                                   \
      if (kt_ + 1 < NKT) STAGE_A(NXT, 0, kt_ + 1)                            \
      __builtin_amdgcn_s_barrier();                                          \
      MFMA_PH(afA, 0)                                                        \
      __builtin_amdgcn_s_barrier();                                          \
      /* ---- p1: MFMA i2-3 (afB);  read afA(i4-5); stage A-h1(kt+1) ---- */ \
      READ_AF(afA, CUR, 4)                                                   \
      if (kt_ + 1 < NKT) STAGE_A(NXT, 1, kt_ + 1)                            \
      __builtin_amdgcn_s_barrier();                                          \
      MFMA_PH(afB, 2)                                                        \
      __builtin_amdgcn_s_barrier();                                          \
      /* ---- p2: MFMA i4-5 (afA);  read afB(i6-7); stage B-h0(kt+2) ---- */ \
      READ_AF(afB, CUR, 6)                                                   \
      if (kt_ + 2 < NKT) STAGE_B(CUR, 0, kt_ + 2)                            \
      __builtin_amdgcn_s_barrier();                                          \
      MFMA_PH(afA, 4)                                                        \
      __builtin_amdgcn_s_barrier();                                          \
      /* ---- p3: stage B-h1(kt+2); counted vmcnt; barrier; then        */   \
      /*      next-tile frag reads bracket the MFMA i6-7 cluster        */   \
      if (kt_ + 2 < NKT) {                                                   \
        STAGE_B(CUR, 1, kt_ + 2)                                             \
        asm volatile("s_waitcnt vmcnt(4)" ::: "memory");                     \
      } else {                                                               \
        asm volatile("s_waitcnt vmcnt(0)" ::: "memory");                     \
      }                                                                      \
      __builtin_amdgcn_s_barrier();                                          \
      if (kt_ + 1 < NKT) READ_AF(afA, NXT, 0)                                \
      MFMA_PH(afB, 6)                                                        \
      if (kt_ + 1 < NKT) READ_BF(NXT)                                        \
      __builtin_amdgcn_s_barrier(); }
    TILE_BODY(0, 1, ktb)
    TILE_BODY(1, 0, ktb + 1)
#undef TILE_BODY
  }

  // ---- epilogue: C/D layout col = lane&15, row = (lane>>4)*4 + reg ----
#pragma unroll
  for (int j = 0; j < 4; ++j) {
    const int col = bn + wn * 64 + j * 16 + lr;
    const float bv = bias[col];
#pragma unroll
    for (int i = 0; i < 8; ++i) {
      const int row0 = bm + wm * 128 + i * 16 + lq * 4;
#pragma unroll
      for (int r = 0; r < 4; ++r)
        __builtin_nontemporal_store(
            acc[i][j][r] + bv, &C[(size_t)(row0 + r) * OUT_F + col]);
    }
  }
}

extern "C" void kernel_launch(void* const* d_in, const int* in_sizes, int n_in,
                              void* d_out, int out_size, void* d_ws, size_t ws_size,
                              hipStream_t stream) {
  const float* x    = (const float*)d_in[0];  // [2,2048,4096] fp32
  const int*   qw   = (const int*)d_in[1];    // [11008,4096] int32 in [-8,7]
  const float* sc   = (const float*)d_in[2];  // [11008,32] fp32
  const float* bias = (const float*)d_in[3];  // [11008] fp32
  float* out = (float*)d_out;                 // [2,2048,11008] fp32

  bf16* wq = (bf16*)d_ws;
  bf16* xb = (bf16*)((char*)d_ws + (size_t)OUT_F * IN_F * sizeof(bf16));

  dequant_w_kernel<<<(OUT_F * IN_F / 8) / 256, 256, 0, stream>>>(qw, sc, wq);
  cast_x_kernel<<<(M_TOT * IN_F / 8) / 256, 256, 0, stream>>>(x, xb);

  gemm_bt_bias_kernel<<<dim3(NWG), 512, 0, stream>>>(xb, wq, bias, out);
}

// Round 3
// 759.244 us; speedup vs baseline: 1.1041x; 1.0130x over previous
//
#include <hip/hip_runtime.h>

#define OUT_F 11008
#define IN_F  4096
#define M_TOT 4096   // 2*2048
#define BM    256
#define BN    256
#define BK    64
#define NKT   (IN_F / BK)    // 64 K-tiles
#define TM_N  (M_TOT / BM)   // 16
#define TN_N  (OUT_F / BN)   // 43
#define NWG   (TM_N * TN_N)  // 688 (== 86*8, XCD-divisible)

typedef __bf16 bf16;
typedef __attribute__((ext_vector_type(8))) __bf16 bf16x8;
typedef __attribute__((ext_vector_type(4))) float  floatx4;

// async global->LDS, 16B per lane; LDS dest = wave-uniform base + lane*16.
#define GLD_LDS16(g, l) __builtin_amdgcn_global_load_lds(                      \
    (const __attribute__((address_space(1))) unsigned int*)(g),                \
    (__attribute__((address_space(3))) unsigned int*)(l), 16, 0, 0)

// ---------------- pre-pass 1: dequant W to bf16 ----------------
__global__ __launch_bounds__(256) void dequant_w_kernel(
    const int* __restrict__ qw, const float* __restrict__ sc,
    bf16* __restrict__ w) {
  const int idx  = blockIdx.x * 256 + threadIdx.x;   // [0, OUT_F*IN_F/8)
  const int o    = idx >> 9;            // / (IN_F/8 = 512)
  const int iv   = idx & 511;           // vector index within row
  const float s  = sc[o * (IN_F / 128) + (iv >> 4)]; // group = (iv*8)>>7
  const int base = idx * 8;
  const int4* p  = (const int4*)(qw + base);
  const int4 q0  = p[0];
  const int4 q1  = p[1];
  bf16x8 v;
  v[0] = (bf16)((float)q0.x * s);
  v[1] = (bf16)((float)q0.y * s);
  v[2] = (bf16)((float)q0.z * s);
  v[3] = (bf16)((float)q0.w * s);
  v[4] = (bf16)((float)q1.x * s);
  v[5] = (bf16)((float)q1.y * s);
  v[6] = (bf16)((float)q1.z * s);
  v[7] = (bf16)((float)q1.w * s);
  *(bf16x8*)(w + base) = v;
}

// ---------------- pre-pass 2: cast x to bf16 ----------------
__global__ __launch_bounds__(256) void cast_x_kernel(
    const float* __restrict__ x, bf16* __restrict__ xb) {
  const int idx  = blockIdx.x * 256 + threadIdx.x;
  const int base = idx * 8;
  const float4* p = (const float4*)(x + base);
  const float4 a = p[0];
  const float4 b = p[1];
  bf16x8 v;
  v[0] = (bf16)a.x; v[1] = (bf16)a.y; v[2] = (bf16)a.z; v[3] = (bf16)a.w;
  v[4] = (bf16)b.x; v[5] = (bf16)b.y; v[6] = (bf16)b.z; v[7] = (bf16)b.w;
  *(bf16x8*)(xb + base) = v;
}

// ---------------- GEMM: 256x256, BK=64, 8-phase, frag-prefetch v3 --------
// C[M][N] = A[M][K] * B[N][K]^T + bias.  512 thr = 8 waves (2M x 4N); wave
// owns 128x64 via acc[8][4] of 16x16x32 MFMA.
// r3 changes vs r2 (33% MfmaUtil):
//  (1) stage both A halves at p0, B halves at p1/p2 -> A-h1 gains a phase of
//      slack before the p3 vmcnt(4); B(kt+1) has ~6 phases.
//  (2) kk-OUTER MFMA order (8 independent MFMAs between dependent acc
//      updates) instead of back-to-back dependent kk pairs.
//  (3) p3 interleaves {MFMA kk1; read new bfr1; MFMA kk0; read new bfr0}
//      so each B-refill drains under an 8-MFMA cluster; p0 consumes
//      kk1-first (the older reads).  Zero extra register pressure.
// vmcnt(4) at p3: in-flight order [B(kt+1)x4, A(kt+1)x4, B(kt+2)x4] ->
// drains exactly the 8 loads tile kt+1 needs; B(kt+2) stays in flight.
__global__ __launch_bounds__(512, 2) void gemm_bt_bias_kernel(
    const bf16* __restrict__ A, const bf16* __restrict__ B,
    const float* __restrict__ bias, float* __restrict__ C) {
  __shared__ bf16 As[2][2][128 * 64];   // 64 KiB
  __shared__ bf16 Bs[2][2][128 * 64];   // 64 KiB

  const int t    = threadIdx.x;
  const int lane = t & 63;
  const int wv   = t >> 6;
  const int wm   = wv >> 2;            // 0/1: A half (M offset /128)
  const int wn   = wv & 3;             // 0..3: N offset /64
  const int lr   = lane & 15;
  const int lq   = lane >> 4;          // 0..3

  // XCD-aware bijective swizzle (NWG % 8 == 0).
  const int bid = blockIdx.x;
  const int swz = (bid & 7) * (NWG / 8) + (bid >> 3);
  const int bm  = (swz % TM_N) * BM;
  const int bn  = (swz / TM_N) * BN;

  // ---- staging coords: thread t stages 16B slots t and t+512 of a half ----
  const int sr  = t >> 3;                 // physical row 0..63 (and +64)
  const int sc  = t & 7;                  // physical 16B chunk
  const int scx = (sc ^ (sr & 7)) * 8;    // inverse-swizzled SOURCE col (elems)
  const bf16* aStg = A + (bm + sr) * IN_F + scx;
  const bf16* bStg = B + (bn + sr) * IN_F + scx;

#define STAGE_A(BUF, H, KT)                                                  \
  { const bf16* g_ = aStg + (H) * 128 * IN_F + (KT) * BK;                    \
    GLD_LDS16(g_, &As[BUF][H][t * 8]);                                       \
    GLD_LDS16(g_ + 64 * IN_F, &As[BUF][H][t * 8 + 4096]); }
#define STAGE_B(BUF, H, KT)                                                  \
  { const bf16* g_ = bStg + (H) * 128 * IN_F + (KT) * BK;                    \
    GLD_LDS16(g_, &Bs[BUF][H][t * 8]);                                       \
    GLD_LDS16(g_ + 64 * IN_F, &Bs[BUF][H][t * 8 + 4096]); }

  // ---- read-side swizzled column offsets (elements within a 64-elem row) ---
  const int xsw = (lr & 7) << 4;              // row-dependent XOR
  const int c0b = (lq * 16) ^ xsw;            // kk=0 physical byte col
  const int e0  = c0b >> 1;
  const int e1  = (c0b ^ 64) >> 1;            // kk=1

  floatx4 acc[8][4];
#pragma unroll
  for (int i = 0; i < 8; i++)
#pragma unroll
    for (int j = 0; j < 4; j++)
      acc[i][j] = (floatx4){0.f, 0.f, 0.f, 0.f};

  bf16x8 afA[2][2], afB[2][2], bfr[4][2];

#define READ_AF(DST, CURB, I0)                                               \
  { const bf16* aB_ = &As[CURB][wm][0];                                      \
    _Pragma("unroll") for (int ii_ = 0; ii_ < 2; ++ii_) {                    \
      const int row_ = ((I0) + ii_) * 16 + lr;                               \
      DST[ii_][0] = *(const bf16x8*)&aB_[row_ * 64 + e0];                    \
      DST[ii_][1] = *(const bf16x8*)&aB_[row_ * 64 + e1]; } }

#define READ_BF_KK(CURB, KK, EK)                                             \
  { const bf16* bB_ = &Bs[CURB][wn >> 1][(wn & 1) * (64 * 64)];              \
    _Pragma("unroll") for (int j_ = 0; j_ < 4; ++j_) {                       \
      const int row_ = j_ * 16 + lr;                                         \
      bfr[j_][KK] = *(const bf16x8*)&bB_[row_ * 64 + (EK)]; } }

  // 8 independent MFMAs (one kk-slice); dependent acc updates are 8 apart.
#define MFMA8(AFS, I0, KK)                                                   \
  _Pragma("unroll") for (int ii_ = 0; ii_ < 2; ++ii_)                        \
    _Pragma("unroll") for (int j_ = 0; j_ < 4; ++j_)                         \
      acc[(I0) + ii_][j_] = __builtin_amdgcn_mfma_f32_16x16x32_bf16(         \
          AFS[ii_][KK], bfr[j_][KK], acc[(I0) + ii_][j_], 0, 0, 0);

#define MFMA16(AFS, I0)                                                      \
  __builtin_amdgcn_s_setprio(1);                                             \
  MFMA8(AFS, I0, 1)                                                          \
  MFMA8(AFS, I0, 0)                                                          \
  __builtin_amdgcn_s_setprio(0);

  // ---- prologue: kt0 fully + kt1's B halves; then first fragments ----
  STAGE_A(0, 0, 0) STAGE_A(0, 1, 0) STAGE_B(0, 0, 0) STAGE_B(0, 1, 0)
  STAGE_B(1, 0, 1) STAGE_B(1, 1, 1)
  asm volatile("s_waitcnt vmcnt(4)" ::: "memory");  // kt0's 8 loads landed
  __builtin_amdgcn_s_barrier();
  READ_AF(afA, 0, 0)
  READ_BF_KK(0, 1, e1)
  READ_BF_KK(0, 0, e0)

  for (int ktb = 0; ktb < NKT; ktb += 2) {
#define TILE_BODY(CUR, NXT, KT)                                              \
    { const int kt_ = (KT);                                                  \
      /* -- p0: read afB(i2-3); stage A h0+h1(kt+1); MFMA i0-1 -- */         \
      READ_AF(afB, CUR, 2)                                                   \
      if (kt_ + 1 < NKT) { STAGE_A(NXT, 0, kt_ + 1)                          \
                           STAGE_A(NXT, 1, kt_ + 1) }                        \
      __builtin_amdgcn_s_barrier();                                          \
      MFMA16(afA, 0)                                                         \
      __builtin_amdgcn_s_barrier();                                          \
      /* -- p1: read afA(i4-5); stage B-h0(kt+2); MFMA i2-3 -- */            \
      READ_AF(afA, CUR, 4)                                                   \
      if (kt_ + 2 < NKT) STAGE_B(CUR, 0, kt_ + 2)                            \
      __builtin_amdgcn_s_barrier();                                          \
      MFMA16(afB, 2)                                                         \
      __builtin_amdgcn_s_barrier();                                          \
      /* -- p2: read afB(i6-7); stage B-h1(kt+2); MFMA i4-5 -- */            \
      READ_AF(afB, CUR, 6)                                                   \
      if (kt_ + 2 < NKT) STAGE_B(CUR, 1, kt_ + 2)                            \
      __builtin_amdgcn_s_barrier();                                          \
      MFMA16(afA, 4)                                                         \
      __builtin_amdgcn_s_barrier();                                          \
      /* -- p3: counted vmcnt; next-tile frag reads interleaved with   */    \
      /*        the kk-split MFMA i6-7 clusters                         */   \
      if (kt_ + 2 < NKT) {                                                   \
        asm volatile("s_waitcnt vmcnt(4)" ::: "memory");                     \
      } else {                                                               \
        asm volatile("s_waitcnt vmcnt(0)" ::: "memory");                     \
      }                                                                      \
      __builtin_amdgcn_s_barrier();                                          \
      if (kt_ + 1 < NKT) READ_AF(afA, NXT, 0)                                \
      __builtin_amdgcn_s_setprio(1);                                         \
      MFMA8(afB, 6, 1)                                                       \
      if (kt_ + 1 < NKT) READ_BF_KK(NXT, 1, e1)                              \
      MFMA8(afB, 6, 0)                                                       \
      __builtin_amdgcn_s_setprio(0);                                         \
      if (kt_ + 1 < NKT) READ_BF_KK(NXT, 0, e0)                              \
      __builtin_amdgcn_s_barrier(); }
    TILE_BODY(0, 1, ktb)
    TILE_BODY(1, 0, ktb + 1)
#undef TILE_BODY
  }

  // ---- epilogue: C/D layout col = lane&15, row = (lane>>4)*4 + reg ----
#pragma unroll
  for (int j = 0; j < 4; ++j) {
    const int col = bn + wn * 64 + j * 16 + lr;
    const float bv = bias[col];
#pragma unroll
    for (int i = 0; i < 8; ++i) {
      const int row0 = bm + wm * 128 + i * 16 + lq * 4;
#pragma unroll
      for (int r = 0; r < 4; ++r)
        __builtin_nontemporal_store(
            acc[i][j][r] + bv, &C[(size_t)(row0 + r) * OUT_F + col]);
    }
  }
}

extern "C" void kernel_launch(void* const* d_in, const int* in_sizes, int n_in,
                              void* d_out, int out_size, void* d_ws, size_t ws_size,
                              hipStream_t stream) {
  const float* x    = (const float*)d_in[0];  // [2,2048,4096] fp32
  const int*   qw   = (const int*)d_in[1];    // [11008,4096] int32 in [-8,7]
  const float* sc   = (const float*)d_in[2];  // [11008,32] fp32
  const float* bias = (const float*)d_in[3];  // [11008] fp32
  float* out = (float*)d_out;                 // [2,2048,11008] fp32

  bf16* wq = (bf16*)d_ws;
  bf16* xb = (bf16*)((char*)d_ws + (size_t)OUT_F * IN_F * sizeof(bf16));

  dequant_w_kernel<<<(OUT_F * IN_F / 8) / 256, 256, 0, stream>>>(qw, sc, wq);
  cast_x_kernel<<<(M_TOT * IN_F / 8) / 256, 256, 0, stream>>>(x, xb);

  gemm_bt_bias_kernel<<<dim3(NWG), 512, 0, stream>>>(xb, wq, bias, out);
}